// Round 8
// baseline (384.482 us; speedup 1.0000x reference)
//
#include <hip/hip_runtime.h>
#include <stdint.h>

typedef __attribute__((ext_vector_type(8))) short bf16x8;
typedef __attribute__((ext_vector_type(4))) float f32x4;
typedef __attribute__((ext_vector_type(4))) unsigned short u16x4;

#define LOG2E 1.44269504088896340736f
#define SCALE 0.0625f

__device__ __forceinline__ unsigned short f32_bf16(float f) {
  unsigned int u = __float_as_uint(f);
  u += 0x7fffu + ((u >> 16) & 1u);
  return (unsigned short)(u >> 16);
}
__device__ __forceinline__ float bf16_f32(unsigned short h) {
  return __uint_as_float(((unsigned int)h) << 16);
}

__device__ __forceinline__ void gload16(const unsigned short* g, unsigned short* l) {
  __builtin_amdgcn_global_load_lds((const __attribute__((address_space(1))) void*)g,
                                   (__attribute__((address_space(3))) void*)l, 16, 0, 0);
}

__device__ __forceinline__ void cast4(const float* __restrict__ in,
                                      unsigned short* __restrict__ out, int i) {
  const float4 v = ((const float4*)in)[i];
  u16x4 o;
  o[0] = f32_bf16(v.x); o[1] = f32_bf16(v.y); o[2] = f32_bf16(v.z); o[3] = f32_bf16(v.w);
  ((u16x4*)out)[i] = o;
}

// ---------------- prep: all input casts + rope table, one launch ----------------
// segments: [0,2097152) hidden | [..,3145728) Wq | [..,3276800) Wk | [..,3407872) Wv
//           [..,3932160) rope table. grid = 3932160/256 = 15360 blocks exact.
__global__ __launch_bounds__(256) void prep(const float* __restrict__ hidden,
                                            const float* __restrict__ Wq,
                                            const float* __restrict__ Wk,
                                            const float* __restrict__ Wv,
                                            const int* __restrict__ pos,
                                            unsigned short* __restrict__ hid_bf,
                                            unsigned short* __restrict__ w_bf,
                                            float* __restrict__ ctab,
                                            float* __restrict__ stab) {
  int i = blockIdx.x * 256 + threadIdx.x;
  if (i < 2097152) {
    cast4(hidden, hid_bf, i);
  } else if (i < 3145728) {
    cast4(Wq, w_bf, i - 2097152);
  } else if (i < 3276800) {
    cast4(Wk, w_bf + 4194304, i - 3145728);
  } else if (i < 3407872) {
    cast4(Wv, w_bf + 4718592, i - 3276800);
  } else {
    int j = i - 3407872;  // 2*2048*128 entries
    int d = j & 127, s = (j >> 7) & 2047, b = j >> 18;
    float p = (float)pos[b * 2048 + s];
    float f = p * exp2f(-(float)d * 0.10381025296523f);
    float sn, c;
    sincosf(f, &sn, &c);
    ctab[j] = c;
    stab[j] = sn;
  }
}

// ---------------- GEMM: C[M][N] = A[M][K] * B[N][K]^T, 2-phase pipeline + XCD swizzle ----
template<int OUTF32>
__global__ __launch_bounds__(256) void gemm_nt(const unsigned short* __restrict__ A,
                                               const unsigned short* __restrict__ B,
                                               void* __restrict__ Cp,
                                               int M, int N, int K) {
  __shared__ unsigned short As[2][128 * 32];
  __shared__ unsigned short Bs[2][128 * 32];
  const int t = threadIdx.x;
  const int lane = t & 63;
  const int wave = t >> 6;
  const int wr = (wave >> 1) * 64;
  const int wc = (wave & 1) * 64;
  const int l15 = lane & 15, lg = lane >> 4;

  const int gx = gridDim.x, gy = gridDim.y;
  int orig = blockIdx.y * gx + blockIdx.x;
  int nwg = gx * gy;
  int wg = orig;
  if ((nwg & 7) == 0) wg = (orig & 7) * (nwg >> 3) + (orig >> 3);
  const int bx = wg / gy, by = wg % gy;
  const long m0 = (long)by * 128;
  const long n0 = (long)bx * 128;

  f32x4 acc[4][4];
#pragma unroll
  for (int m = 0; m < 4; ++m)
#pragma unroll
    for (int n = 0; n < 4; ++n) acc[m][n] = (f32x4){0.f, 0.f, 0.f, 0.f};

  const int srow = t >> 2;
  const int scol = (t & 3) * 8;
  const unsigned short* Ag = A + (m0 + srow) * (long)K + scol;
  const unsigned short* Bg = B + (n0 + srow) * (long)K + scol;

  auto stage = [&](int buf, int k0) {
    gload16(Ag + k0, &As[buf][t * 8]);
    gload16(Ag + (long)64 * K + k0, &As[buf][2048 + t * 8]);
    gload16(Bg + k0, &Bs[buf][t * 8]);
    gload16(Bg + (long)64 * K + k0, &Bs[buf][2048 + t * 8]);
  };

  stage(0, 0);
  __syncthreads();
  int cur = 0;
  for (int k0 = 0; k0 < K; k0 += 32) {
    if (k0 + 32 < K) stage(cur ^ 1, k0 + 32);
    bf16x8 af[4], bfr[4];
#pragma unroll
    for (int m = 0; m < 4; ++m) af[m] = *(const bf16x8*)&As[cur][(wr + m * 16 + l15) * 32 + lg * 8];
#pragma unroll
    for (int n = 0; n < 4; ++n) bfr[n] = *(const bf16x8*)&Bs[cur][(wc + n * 16 + l15) * 32 + lg * 8];
    __builtin_amdgcn_s_setprio(1);
#pragma unroll
    for (int m = 0; m < 4; ++m)
#pragma unroll
      for (int n = 0; n < 4; ++n)
        acc[m][n] = __builtin_amdgcn_mfma_f32_16x16x32_bf16(af[m], bfr[n], acc[m][n], 0, 0, 0);
    __builtin_amdgcn_s_setprio(0);
    __syncthreads();
    cur ^= 1;
  }

#pragma unroll
  for (int m = 0; m < 4; ++m)
#pragma unroll
    for (int n = 0; n < 4; ++n)
#pragma unroll
      for (int r = 0; r < 4; ++r) {
        long row = m0 + wr + m * 16 + lg * 4 + r;
        long col = n0 + wc + n * 16 + l15;
        if (OUTF32)
          ((float*)Cp)[row * N + col] = acc[m][n][r];
        else
          ((unsigned short*)Cp)[row * N + col] = f32_bf16(acc[m][n][r]);
      }
}

// ---------------- mid: rope-apply (+SCALE fold on Q) + V transpose + Wo cast ----------------
// blocks [0,2304): rope | [2304,2560): transpose_v | [2560,6656): Wo cast
__global__ __launch_bounds__(256) void mid(unsigned short* __restrict__ qkv,
                                           const float* __restrict__ ctab,
                                           const float* __restrict__ stab,
                                           unsigned short* __restrict__ vt,
                                           const float* __restrict__ Wo,
                                           unsigned short* __restrict__ wo_bf) {
  __shared__ unsigned short tile[64][68];
  const int bi = blockIdx.x, t = threadIdx.x;
  if (bi < 2304) {
    int i = bi * 256 + t;  // 2*2048*9*16 exact
    int g = i & 15;
    int hh = (i >> 4) % 9;
    int sb_ = (i >> 4) / 9;
    int s = sb_ & 2047, b = sb_ >> 11;
    size_t base = (size_t)(b * 2048 + s) * 2560 + (hh == 8 ? 2048 : hh * 256) + g * 8;
    const float* ct = ctab + ((size_t)(b * 2048 + s) << 7) + g * 8;
    const float* st = stab + ((size_t)(b * 2048 + s) << 7) + g * 8;
    const float sc = (hh == 8) ? 1.0f : SCALE;  // fold attention scale into Q
    bf16x8 lo = *(const bf16x8*)(qkv + base);
    bf16x8 hi = *(const bf16x8*)(qkv + base + 128);
    bf16x8 lo2, hi2;
#pragma unroll
    for (int e = 0; e < 8; ++e) {
      float c = ct[e] * sc, sn = st[e] * sc;
      float x1 = bf16_f32((unsigned short)lo[e]);
      float x2 = bf16_f32((unsigned short)hi[e]);
      lo2[e] = (short)f32_bf16(x1 * c - x2 * sn);
      hi2[e] = (short)f32_bf16(x2 * c + x1 * sn);
    }
    *(bf16x8*)(qkv + base) = lo2;
    *(bf16x8*)(qkv + base + 128) = hi2;
  } else if (bi < 2560) {
    int bb = bi - 2304;
    const int s0 = (bb & 31) * 64, d0 = ((bb >> 5) & 3) * 64, b = bb >> 7;
    const int r = t >> 4, c4 = (t & 15) * 4;
#pragma unroll
    for (int j = 0; j < 4; ++j) {
      int row = r + j * 16;
      const unsigned short* src = qkv + (size_t)(b * 2048 + s0 + row) * 2560 + 2304 + d0 + c4;
#pragma unroll
      for (int e = 0; e < 4; ++e) tile[row][c4 + e] = src[e];
    }
    __syncthreads();
#pragma unroll
    for (int j = 0; j < 4; ++j) {
      int drow = r + j * 16;
      u16x4 o;
#pragma unroll
      for (int e = 0; e < 4; ++e) o[e] = tile[c4 + e][drow];
      *(u16x4*)(vt + (size_t)(b * 256 + d0 + drow) * 2048 + s0 + c4) = o;
    }
  } else {
    int i = (bi - 2560) * 256 + t;  // 1048576 exact
    cast4(Wo, wo_bf, i);
  }
}

// ------- flash attention: swapped QK^T, K LDS-staged (dbuf), V direct from L2 -------
__global__ __launch_bounds__(256, 2) void attn3(const unsigned short* __restrict__ qkv,
                                                const unsigned short* __restrict__ vt,
                                                unsigned short* __restrict__ O) {
  __shared__ __align__(16) unsigned short Ks[2][32 * 256];  // 32 keys x 256 d, swz (row&7)<<4
  const int t = threadIdx.x, lane = t & 63, wave = t >> 6;
  const int l15 = lane & 15, lg = lane >> 4;
  const int qb = blockIdx.x, h = blockIdx.y, b = blockIdx.z;
  const int q0 = qb * 64;
  const int qw = q0 + wave * 16;        // wave's first q row
  const int qg = qw + l15;              // this lane's q row

  // Q as B-frags (already pre-scaled by SCALE in mid/rope)
  bf16x8 qf[8];
  {
    const unsigned short* qp = qkv + (size_t)(b * 2048 + qg) * 2560 + h * 256 + lg * 8;
#pragma unroll
    for (int c = 0; c < 8; ++c) qf[c] = *(const bf16x8*)(qp + c * 32);
  }

  // K staging addresses (pre-swizzled global source, linear LDS dest)
  size_t kgb[4];
  int klo[4];
#pragma unroll
  for (int p = 0; p < 4; ++p) {
    int i = p * 256 + t;
    int kr = i >> 5, kb = (i & 31) << 4;
    int ksrc = kb ^ ((kr & 7) << 4);
    kgb[p] = (size_t)(b * 2048 + kr) * 2560 + 2048 + (ksrc >> 1);
    klo[p] = i * 8;
  }

  // V base for direct frag loads: row d = dt*16+l15, key col ks + lg*8
  const unsigned short* vbase = vt + (size_t)b * 524288 + (size_t)l15 * 2048 + lg * 8;

  f32x4 oacc[16];
#pragma unroll
  for (int dt = 0; dt < 16; ++dt) oacc[dt] = (f32x4){0.f, 0.f, 0.f, 0.f};
  float mrun = -3e30f, lrun = 0.f;

  int ks0 = q0 - 1023;
  if (ks0 < 0) ks0 = 0;
  ks0 &= ~31;
  const int nst = (q0 + 64 - ks0) >> 5;

  // prologue: K tile0 -> buf0
#pragma unroll
  for (int p = 0; p < 4; ++p) gload16(qkv + kgb[p] + (size_t)ks0 * 2560, &Ks[0][klo[p]]);
  __syncthreads();

  for (int si = 0; si < nst; ++si) {
    const int ks = ks0 + si * 32;
    const int cur = si & 1;
    if (si + 1 < nst) {  // stage next K tile (uniform)
      const size_t ko = (size_t)(ks + 32) * 2560;
#pragma unroll
      for (int p = 0; p < 4; ++p) gload16(qkv + kgb[p] + ko, &Ks[cur ^ 1][klo[p]]);
    }

    // fully-masked step for this wave? (still participates in staging + barrier)
    const bool live = !((ks > qw + 15) || (ks + 31 <= qw - 1024));
    if (live) {
      // issue V frags early: L2 latency hides under QK^T + softmax
      bf16x8 vf[16];
#pragma unroll
      for (int dt = 0; dt < 16; ++dt)
        vf[dt] = *(const bf16x8*)(vbase + (size_t)dt * 32768 + ks);

      // S^T = K · Q^T : lane holds S[key = n*16 + lg*4 + r][q = l15]
      const unsigned short* Kc = Ks[cur];
      f32x4 sa = (f32x4){0.f, 0.f, 0.f, 0.f};
      f32x4 sb2 = (f32x4){0.f, 0.f, 0.f, 0.f};
      const int kswz = (l15 & 7) << 4;
      __builtin_amdgcn_s_setprio(1);
#pragma unroll
      for (int c = 0; c < 8; ++c) {
        const int off = ((c * 64 + lg * 16) ^ kswz) >> 1;
        bf16x8 k0 = *(const bf16x8*)&Kc[l15 * 256 + off];
        bf16x8 k1 = *(const bf16x8*)&Kc[(16 + l15) * 256 + off];
        sa = __builtin_amdgcn_mfma_f32_16x16x32_bf16(k0, qf[c], sa, 0, 0, 0);
        sb2 = __builtin_amdgcn_mfma_f32_16x16x32_bf16(k1, qf[c], sb2, 0, 0, 0);
      }
      __builtin_amdgcn_s_setprio(0);

      // mask (wave-uniform fast path for interior steps) + online softmax
      float pv[8];
      const bool full = (ks + 31 <= qw) && (ks > qw - 1009);
      if (full) {
#pragma unroll
        for (int r = 0; r < 4; ++r) { pv[r] = sa[r]; pv[4 + r] = sb2[r]; }
      } else {
        const int kb0 = ks + lg * 4, kb1 = kb0 + 16;
        const int lo_b = qg - 1024;
#pragma unroll
        for (int r = 0; r < 4; ++r) {
          int k0i = kb0 + r, k1i = kb1 + r;
          pv[r] = (k0i <= qg && k0i > lo_b) ? sa[r] : -3e38f;
          pv[4 + r] = (k1i <= qg && k1i > lo_b) ? sb2[r] : -3e38f;
        }
      }
      float mx = fmaxf(fmaxf(fmaxf(pv[0], pv[1]), fmaxf(pv[2], pv[3])),
                       fmaxf(fmaxf(pv[4], pv[5]), fmaxf(pv[6], pv[7])));
      mx = fmaxf(mx, __shfl_xor(mx, 16));
      mx = fmaxf(mx, __shfl_xor(mx, 32));
      if (!__all(mx - mrun <= 8.0f)) {  // defer-max (T13)
        float mnew = fmaxf(mrun, mx);
        float al = exp2f((mrun - mnew) * LOG2E);
#pragma unroll
        for (int dt = 0; dt < 16; ++dt) oacc[dt] *= al;
        lrun *= al;
        mrun = mnew;
      }
      float ps = 0.f;
#pragma unroll
      for (int j = 0; j < 8; ++j) {
        pv[j] = exp2f((pv[j] - mrun) * LOG2E);
        ps += pv[j];
      }
      ps += __shfl_xor(ps, 16);
      ps += __shfl_xor(ps, 32);
      lrun += ps;

      // pack P to bf16 pairs: w0,w1 = tile0 keys (lg*4..+3); w2,w3 = tile1
      unsigned int w0 = ((unsigned int)f32_bf16(pv[1]) << 16) | f32_bf16(pv[0]);
      unsigned int w1 = ((unsigned int)f32_bf16(pv[3]) << 16) | f32_bf16(pv[2]);
      unsigned int w2 = ((unsigned int)f32_bf16(pv[5]) << 16) | f32_bf16(pv[4]);
      unsigned int w3 = ((unsigned int)f32_bf16(pv[7]) << 16) | f32_bf16(pv[6]);
      // conflict-free XOR redistribution into P^T B-frag
      unsigned int sA0 = (lg < 2) ? w2 : w0;
      unsigned int sA1 = (lg < 2) ? w3 : w1;
      unsigned int rA0 = (unsigned int)__shfl_xor((int)sA0, 32);
      unsigned int rA1 = (unsigned int)__shfl_xor((int)sA1, 32);
      unsigned int own0 = (lg < 2) ? w0 : w2;
      unsigned int own1 = (lg < 2) ? w1 : w3;
      const bool sendOwn = ((lg ^ (lg >> 1)) & 1) != 0;
      unsigned int sB0 = sendOwn ? own0 : rA0;
      unsigned int sB1 = sendOwn ? own1 : rA1;
      unsigned int rB0 = (unsigned int)__shfl_xor((int)sB0, 16);
      unsigned int rB1 = (unsigned int)__shfl_xor((int)sB1, 16);
      union { unsigned int u[4]; bf16x8 v; } pu;
      pu.u[0] = (lg == 0) ? own0 : ((lg == 2) ? rA0 : rB0);
      pu.u[1] = (lg == 0) ? own1 : ((lg == 2) ? rA1 : rB1);
      pu.u[2] = (lg == 3) ? own0 : ((lg == 1) ? rA0 : rB0);
      pu.u[3] = (lg == 3) ? own1 : ((lg == 1) ? rA1 : rB1);

      // PV: O^T[d][q] += V^T-frag (A, from regs) * P^T-frag (B)
      __builtin_amdgcn_s_setprio(1);
#pragma unroll
      for (int dt = 0; dt < 16; ++dt)
        oacc[dt] = __builtin_amdgcn_mfma_f32_16x16x32_bf16(vf[dt], pu.v, oacc[dt], 0, 0, 0);
      __builtin_amdgcn_s_setprio(0);
    }
    __syncthreads();  // drains vmcnt (next K tile staged) + all waves done with cur
  }

  // epilogue: lane holds O^T[d = dt*16 + lg*4 + r][q = qg]
  float inv = 1.0f / lrun;
  unsigned short* op = O + (size_t)(b * 2048 + qg) * 2048 + h * 256 + lg * 4;
#pragma unroll
  for (int dt = 0; dt < 16; ++dt) {
    u16x4 o4;
#pragma unroll
    for (int r = 0; r < 4; ++r) o4[r] = f32_bf16(oacc[dt][r] * inv);
    *(u16x4*)(op + dt * 16) = o4;
  }
}

// ---------------- launch: 5 kernels ----------------
extern "C" void kernel_launch(void* const* d_in, const int* in_sizes, int n_in,
                              void* d_out, int out_size, void* d_ws, size_t ws_size,
                              hipStream_t stream) {
  const float* hidden = (const float*)d_in[0];
  // d_in[1]: attention_mask (pure causal; handled analytically)
  const int* pos_ids = (const int*)d_in[2];
  const float* Wq = (const float*)d_in[3];
  const float* Wk = (const float*)d_in[4];
  const float* Wv = (const float*)d_in[5];
  const float* Wo = (const float*)d_in[6];
  float* out = (float*)d_out;
  char* ws = (char*)d_ws;

  unsigned short* qkv_bf = (unsigned short*)(ws);              // 20 MB: [4096][2560]
  unsigned short* hid_bf = (unsigned short*)(ws + 20971520);   // 16 MB (reused as attn out)
  unsigned short* w_bf   = (unsigned short*)(ws + 37748736);   // 10 MB (Wq|Wk|Wv, later Wo)
  unsigned short* vtbuf  = (unsigned short*)(ws + 48234496);   // 2 MB [b][256][2048]
  float*          ctab   = (float*)(ws + 50331648);            // 2 MB
  float*          stab   = (float*)(ws + 52428800);            // 2 MB
  unsigned short* attno  = hid_bf;                             // alias: hidden dead after qkv GEMM

  // 1) all casts + rope table
  prep<<<15360, 256, 0, stream>>>(hidden, Wq, Wk, Wv, pos_ids, hid_bf, w_bf, ctab, stab);

  // 2) fused QKV projection (grid 640 blocks, %8==0)
  gemm_nt<0><<<dim3(20, 32), 256, 0, stream>>>(hid_bf, w_bf, qkv_bf, 4096, 2560, 2048);

  // 3) rope apply (+SCALE into Q) + V transpose + Wo cast (w_bf now free)
  mid<<<6656, 256, 0, stream>>>(qkv_bf, ctab, stab, vtbuf, Wo, w_bf);

  // 4) attention
  attn3<<<dim3(32, 8, 2), 256, 0, stream>>>(qkv_bf, vtbuf, attno);

  // 5) output projection (f32 out; grid 512 blocks, %8==0)
  gemm_nt<1><<<dim3(16, 32), 256, 0, stream>>>(attno, w_bf, out, 4096, 2048, 2048);
}

// Round 10
// 351.656 us; speedup vs baseline: 1.0933x; 1.0933x over previous
//
#include <hip/hip_runtime.h>
#include <stdint.h>

typedef __attribute__((ext_vector_type(8))) short bf16x8;
typedef __attribute__((ext_vector_type(4))) float f32x4;
typedef __attribute__((ext_vector_type(4))) unsigned short u16x4;

#define LOG2E 1.44269504088896340736f
#define SCALE 0.0625f

__device__ __forceinline__ unsigned short f32_bf16(float f) {
  unsigned int u = __float_as_uint(f);
  u += 0x7fffu + ((u >> 16) & 1u);
  return (unsigned short)(u >> 16);
}
__device__ __forceinline__ float bf16_f32(unsigned short h) {
  return __uint_as_float(((unsigned int)h) << 16);
}

__device__ __forceinline__ void gload16(const unsigned short* g, unsigned short* l) {
  __builtin_amdgcn_global_load_lds((const __attribute__((address_space(1))) void*)g,
                                   (__attribute__((address_space(3))) void*)l, 16, 0, 0);
}

__device__ __forceinline__ void cast4(const float* __restrict__ in,
                                      unsigned short* __restrict__ out, int i) {
  const float4 v = ((const float4*)in)[i];
  u16x4 o;
  o[0] = f32_bf16(v.x); o[1] = f32_bf16(v.y); o[2] = f32_bf16(v.z); o[3] = f32_bf16(v.w);
  ((u16x4*)out)[i] = o;
}

// ---------------- prep: all input casts + rope table, one launch ----------------
__global__ __launch_bounds__(256) void prep(const float* __restrict__ hidden,
                                            const float* __restrict__ Wq,
                                            const float* __restrict__ Wk,
                                            const float* __restrict__ Wv,
                                            const int* __restrict__ pos,
                                            unsigned short* __restrict__ hid_bf,
                                            unsigned short* __restrict__ w_bf,
                                            float* __restrict__ ctab,
                                            float* __restrict__ stab) {
  int i = blockIdx.x * 256 + threadIdx.x;
  if (i < 2097152) {
    cast4(hidden, hid_bf, i);
  } else if (i < 3145728) {
    cast4(Wq, w_bf, i - 2097152);
  } else if (i < 3276800) {
    cast4(Wk, w_bf + 4194304, i - 3145728);
  } else if (i < 3407872) {
    cast4(Wv, w_bf + 4718592, i - 3276800);
  } else {
    int j = i - 3407872;  // 2*2048*128 entries
    int d = j & 127, s = (j >> 7) & 2047, b = j >> 18;
    float p = (float)pos[b * 2048 + s];
    float f = p * exp2f(-(float)d * 0.10381025296523f);
    float sn, c;
    sincosf(f, &sn, &c);
    ctab[j] = c;
    stab[j] = sn;
  }
}

// ---------------- GEMM: C[M][N] = A[M][K] * B[N][K]^T, 2-phase pipeline + XCD swizzle ----
template<int OUTF32>
__global__ __launch_bounds__(256) void gemm_nt(const unsigned short* __restrict__ A,
                                               const unsigned short* __restrict__ B,
                                               void* __restrict__ Cp,
                                               int M, int N, int K) {
  __shared__ unsigned short As[2][128 * 32];
  __shared__ unsigned short Bs[2][128 * 32];
  const int t = threadIdx.x;
  const int lane = t & 63;
  const int wave = t >> 6;
  const int wr = (wave >> 1) * 64;
  const int wc = (wave & 1) * 64;
  const int l15 = lane & 15, lg = lane >> 4;

  const int gx = gridDim.x, gy = gridDim.y;
  int orig = blockIdx.y * gx + blockIdx.x;
  int nwg = gx * gy;
  int wg = orig;
  if ((nwg & 7) == 0) wg = (orig & 7) * (nwg >> 3) + (orig >> 3);
  const int bx = wg / gy, by = wg % gy;
  const long m0 = (long)by * 128;
  const long n0 = (long)bx * 128;

  f32x4 acc[4][4];
#pragma unroll
  for (int m = 0; m < 4; ++m)
#pragma unroll
    for (int n = 0; n < 4; ++n) acc[m][n] = (f32x4){0.f, 0.f, 0.f, 0.f};

  const int srow = t >> 2;
  const int scol = (t & 3) * 8;
  const unsigned short* Ag = A + (m0 + srow) * (long)K + scol;
  const unsigned short* Bg = B + (n0 + srow) * (long)K + scol;

  auto stage = [&](int buf, int k0) {
    gload16(Ag + k0, &As[buf][t * 8]);
    gload16(Ag + (long)64 * K + k0, &As[buf][2048 + t * 8]);
    gload16(Bg + k0, &Bs[buf][t * 8]);
    gload16(Bg + (long)64 * K + k0, &Bs[buf][2048 + t * 8]);
  };

  stage(0, 0);
  __syncthreads();
  int cur = 0;
  for (int k0 = 0; k0 < K; k0 += 32) {
    if (k0 + 32 < K) stage(cur ^ 1, k0 + 32);
    bf16x8 af[4], bfr[4];
#pragma unroll
    for (int m = 0; m < 4; ++m) af[m] = *(const bf16x8*)&As[cur][(wr + m * 16 + l15) * 32 + lg * 8];
#pragma unroll
    for (int n = 0; n < 4; ++n) bfr[n] = *(const bf16x8*)&Bs[cur][(wc + n * 16 + l15) * 32 + lg * 8];
    __builtin_amdgcn_s_setprio(1);
#pragma unroll
    for (int m = 0; m < 4; ++m)
#pragma unroll
      for (int n = 0; n < 4; ++n)
        acc[m][n] = __builtin_amdgcn_mfma_f32_16x16x32_bf16(af[m], bfr[n], acc[m][n], 0, 0, 0);
    __builtin_amdgcn_s_setprio(0);
    __syncthreads();
    cur ^= 1;
  }

#pragma unroll
  for (int m = 0; m < 4; ++m)
#pragma unroll
    for (int n = 0; n < 4; ++n)
#pragma unroll
      for (int r = 0; r < 4; ++r) {
        long row = m0 + wr + m * 16 + lg * 4 + r;
        long col = n0 + wc + n * 16 + l15;
        if (OUTF32)
          ((float*)Cp)[row * N + col] = acc[m][n][r];
        else
          ((unsigned short*)Cp)[row * N + col] = f32_bf16(acc[m][n][r]);
      }
}

// ---------------- mid: rope-apply (+SCALE fold on Q) + V transpose + Wo cast ----------------
__global__ __launch_bounds__(256) void mid(unsigned short* __restrict__ qkv,
                                           const float* __restrict__ ctab,
                                           const float* __restrict__ stab,
                                           unsigned short* __restrict__ vt,
                                           const float* __restrict__ Wo,
                                           unsigned short* __restrict__ wo_bf) {
  __shared__ unsigned short tile[64][68];
  const int bi = blockIdx.x, t = threadIdx.x;
  if (bi < 2304) {
    int i = bi * 256 + t;  // 2*2048*9*16 exact
    int g = i & 15;
    int hh = (i >> 4) % 9;
    int sb_ = (i >> 4) / 9;
    int s = sb_ & 2047, b = sb_ >> 11;
    size_t base = (size_t)(b * 2048 + s) * 2560 + (hh == 8 ? 2048 : hh * 256) + g * 8;
    const float* ct = ctab + ((size_t)(b * 2048 + s) << 7) + g * 8;
    const float* st = stab + ((size_t)(b * 2048 + s) << 7) + g * 8;
    const float sc = (hh == 8) ? 1.0f : SCALE;  // fold attention scale into Q
    bf16x8 lo = *(const bf16x8*)(qkv + base);
    bf16x8 hi = *(const bf16x8*)(qkv + base + 128);
    bf16x8 lo2, hi2;
#pragma unroll
    for (int e = 0; e < 8; ++e) {
      float c = ct[e] * sc, sn = st[e] * sc;
      float x1 = bf16_f32((unsigned short)lo[e]);
      float x2 = bf16_f32((unsigned short)hi[e]);
      lo2[e] = (short)f32_bf16(x1 * c - x2 * sn);
      hi2[e] = (short)f32_bf16(x2 * c + x1 * sn);
    }
    *(bf16x8*)(qkv + base) = lo2;
    *(bf16x8*)(qkv + base + 128) = hi2;
  } else if (bi < 2560) {
    int bb = bi - 2304;
    const int s0 = (bb & 31) * 64, d0 = ((bb >> 5) & 3) * 64, b = bb >> 7;
    const int r = t >> 4, c4 = (t & 15) * 4;
#pragma unroll
    for (int j = 0; j < 4; ++j) {
      int row = r + j * 16;
      const unsigned short* src = qkv + (size_t)(b * 2048 + s0 + row) * 2560 + 2304 + d0 + c4;
#pragma unroll
      for (int e = 0; e < 4; ++e) tile[row][c4 + e] = src[e];
    }
    __syncthreads();
#pragma unroll
    for (int j = 0; j < 4; ++j) {
      int drow = r + j * 16;
      u16x4 o;
#pragma unroll
      for (int e = 0; e < 4; ++e) o[e] = tile[c4 + e][drow];
      *(u16x4*)(vt + (size_t)(b * 256 + d0 + drow) * 2048 + s0 + c4) = o;
    }
  } else {
    int i = (bi - 2560) * 256 + t;  // 1048576 exact
    cast4(Wo, wo_bf, i);
  }
}

// ------- flash attention: swapped QK^T, K gload_lds-dbuf, V single-buffer + T14 reg-stage -------
// LDS 48KB -> 3 blocks/CU; V(si+1) loaded to regs early (latency hides under compute),
// ds_write after barrier1, published by barrier2 (V not read until PV -> max slack).
__global__ __launch_bounds__(256, 3) void attn4(const unsigned short* __restrict__ qkv,
                                                const unsigned short* __restrict__ vt,
                                                unsigned short* __restrict__ O) {
  __shared__ __align__(16) unsigned short Ks[2][32 * 256];  // dbuf, swz (row&7)<<4
  __shared__ __align__(16) unsigned short Vs[256 * 32];     // single, swz ((row>>1)&3)<<4
  const int t = threadIdx.x, lane = t & 63, wave = t >> 6;
  const int l15 = lane & 15, lg = lane >> 4;
  const int qb = blockIdx.x, h = blockIdx.y, b = blockIdx.z;
  const int q0 = qb * 64;
  const int qw = q0 + wave * 16;
  const int qg = qw + l15;

  // Q as B-frags (pre-scaled by SCALE in mid/rope)
  bf16x8 qf[8];
  {
    const unsigned short* qp = qkv + (size_t)(b * 2048 + qg) * 2560 + h * 256 + lg * 8;
#pragma unroll
    for (int c = 0; c < 8; ++c) qf[c] = *(const bf16x8*)(qp + c * 32);
  }

  // staging addresses (pre-swizzled global source, linear LDS dest)
  size_t kgb[4], vgb[4];
  int klo[4], vlo[4];
#pragma unroll
  for (int p = 0; p < 4; ++p) {
    int i = p * 256 + t;
    int kr = i >> 5, kb = (i & 31) << 4;
    int ksrc = kb ^ ((kr & 7) << 4);
    kgb[p] = (size_t)(b * 2048 + kr) * 2560 + 2048 + (ksrc >> 1);
    klo[p] = i * 8;
    int vr = i >> 2, vb = (i & 3) << 4;
    int vsrc = vb ^ (((vr >> 1) & 3) << 4);
    vgb[p] = (size_t)(b * 256 + vr) * 2048 + (vsrc >> 1);
    vlo[p] = i * 8;
  }

  f32x4 oacc[16];
#pragma unroll
  for (int dt = 0; dt < 16; ++dt) oacc[dt] = (f32x4){0.f, 0.f, 0.f, 0.f};
  float mrun = -3e30f, lrun = 0.f;

  int ks0 = q0 - 1023;
  if (ks0 < 0) ks0 = 0;
  ks0 &= ~31;
  const int nst = (q0 + 64 - ks0) >> 5;

  // prologue: K tile0 -> Ks[0], V tile0 -> Vs
#pragma unroll
  for (int p = 0; p < 4; ++p) gload16(qkv + kgb[p] + (size_t)ks0 * 2560, &Ks[0][klo[p]]);
#pragma unroll
  for (int p = 0; p < 4; ++p) gload16(vt + vgb[p] + ks0, &Vs[vlo[p]]);
  __syncthreads();

  for (int si = 0; si < nst; ++si) {
    const int ks = ks0 + si * 32;
    const int cur = si & 1;
    const bool havenext = (si + 1 < nst);
    bf16x8 vst[4];
    if (havenext) {  // uniform: stage K(si+1) async into Ks dbuf; V(si+1) into regs (T14)
      const size_t ko = (size_t)(ks + 32) * 2560;
#pragma unroll
      for (int p = 0; p < 4; ++p) gload16(qkv + kgb[p] + ko, &Ks[cur ^ 1][klo[p]]);
#pragma unroll
      for (int p = 0; p < 4; ++p) vst[p] = *(const bf16x8*)(vt + vgb[p] + (ks + 32));
    }

    // fully-masked step for this wave? (still does staging + barriers)
    const bool live = !((ks > qw + 15) || (ks + 31 <= qw - 1024));
    if (live) {
      // S^T = K · Q^T : lane holds S[key = n*16 + lg*4 + r][q = l15]
      const unsigned short* Kc = Ks[cur];
      f32x4 sa = (f32x4){0.f, 0.f, 0.f, 0.f};
      f32x4 sb2 = (f32x4){0.f, 0.f, 0.f, 0.f};
      const int kswz = (l15 & 7) << 4;
      __builtin_amdgcn_s_setprio(1);
#pragma unroll
      for (int c = 0; c < 8; ++c) {
        const int off = ((c * 64 + lg * 16) ^ kswz) >> 1;
        bf16x8 k0 = *(const bf16x8*)&Kc[l15 * 256 + off];
        bf16x8 k1 = *(const bf16x8*)&Kc[(16 + l15) * 256 + off];
        sa = __builtin_amdgcn_mfma_f32_16x16x32_bf16(k0, qf[c], sa, 0, 0, 0);
        sb2 = __builtin_amdgcn_mfma_f32_16x16x32_bf16(k1, qf[c], sb2, 0, 0, 0);
      }
      __builtin_amdgcn_s_setprio(0);

      // mask (wave-uniform full-window fast path) + online softmax
      float pv[8];
      const bool full = (ks + 31 <= qw) && (ks > qw - 1009);
      if (full) {
#pragma unroll
        for (int r = 0; r < 4; ++r) { pv[r] = sa[r]; pv[4 + r] = sb2[r]; }
      } else {
        const int kb0 = ks + lg * 4, kb1 = kb0 + 16;
        const int lo_b = qg - 1024;
#pragma unroll
        for (int r = 0; r < 4; ++r) {
          int k0i = kb0 + r, k1i = kb1 + r;
          pv[r] = (k0i <= qg && k0i > lo_b) ? sa[r] : -3e38f;
          pv[4 + r] = (k1i <= qg && k1i > lo_b) ? sb2[r] : -3e38f;
        }
      }
      float mx = fmaxf(fmaxf(fmaxf(pv[0], pv[1]), fmaxf(pv[2], pv[3])),
                       fmaxf(fmaxf(pv[4], pv[5]), fmaxf(pv[6], pv[7])));
      mx = fmaxf(mx, __shfl_xor(mx, 16));
      mx = fmaxf(mx, __shfl_xor(mx, 32));
      if (!__all(mx - mrun <= 8.0f)) {  // defer-max (T13)
        float mnew = fmaxf(mrun, mx);
        float al = exp2f((mrun - mnew) * LOG2E);
#pragma unroll
        for (int dt = 0; dt < 16; ++dt) oacc[dt] *= al;
        lrun *= al;
        mrun = mnew;
      }
      float ps = 0.f;
#pragma unroll
      for (int j = 0; j < 8; ++j) {
        pv[j] = exp2f((pv[j] - mrun) * LOG2E);
        ps += pv[j];
      }
      ps += __shfl_xor(ps, 16);
      ps += __shfl_xor(ps, 32);
      lrun += ps;

      // pack P to bf16 pairs + conflict-free XOR redistribution into P^T B-frag
      unsigned int w0 = ((unsigned int)f32_bf16(pv[1]) << 16) | f32_bf16(pv[0]);
      unsigned int w1 = ((unsigned int)f32_bf16(pv[3]) << 16) | f32_bf16(pv[2]);
      unsigned int w2 = ((unsigned int)f32_bf16(pv[5]) << 16) | f32_bf16(pv[4]);
      unsigned int w3 = ((unsigned int)f32_bf16(pv[7]) << 16) | f32_bf16(pv[6]);
      unsigned int sA0 = (lg < 2) ? w2 : w0;
      unsigned int sA1 = (lg < 2) ? w3 : w1;
      unsigned int rA0 = (unsigned int)__shfl_xor((int)sA0, 32);
      unsigned int rA1 = (unsigned int)__shfl_xor((int)sA1, 32);
      unsigned int own0 = (lg < 2) ? w0 : w2;
      unsigned int own1 = (lg < 2) ? w1 : w3;
      const bool sendOwn = ((lg ^ (lg >> 1)) & 1) != 0;
      unsigned int sB0 = sendOwn ? own0 : rA0;
      unsigned int sB1 = sendOwn ? own1 : rA1;
      unsigned int rB0 = (unsigned int)__shfl_xor((int)sB0, 16);
      unsigned int rB1 = (unsigned int)__shfl_xor((int)sB1, 16);
      union { unsigned int u[4]; bf16x8 v; } pu;
      pu.u[0] = (lg == 0) ? own0 : ((lg == 2) ? rA0 : rB0);
      pu.u[1] = (lg == 0) ? own1 : ((lg == 2) ? rA1 : rB1);
      pu.u[2] = (lg == 3) ? own0 : ((lg == 1) ? rA0 : rB0);
      pu.u[3] = (lg == 3) ? own1 : ((lg == 1) ? rA1 : rB1);

      // PV: O^T[d][q] += V^T-frag (A, from Vs) * P^T-frag (B)
      const int vswz = (lg * 16) ^ (((l15 >> 1) & 3) << 4);
      __builtin_amdgcn_s_setprio(1);
#pragma unroll
      for (int dt = 0; dt < 16; ++dt) {
        bf16x8 vf = *(const bf16x8*)&Vs[(dt * 16 + l15) * 32 + (vswz >> 1)];
        oacc[dt] = __builtin_amdgcn_mfma_f32_16x16x32_bf16(vf, pu.v, oacc[dt], 0, 0, 0);
      }
      __builtin_amdgcn_s_setprio(0);
    }
    __syncthreads();  // all waves done reading Vs/Ks[cur]; drains K gloads (Ks[cur^1] ready)
    if (havenext) {
#pragma unroll
      for (int p = 0; p < 4; ++p) *(bf16x8*)&Vs[vlo[p]] = vst[p];
    }
    __syncthreads();  // V(si+1) visible
  }

  // epilogue: lane holds O^T[d = dt*16 + lg*4 + r][q = qg]
  float inv = 1.0f / lrun;
  unsigned short* op = O + (size_t)(b * 2048 + qg) * 2048 + h * 256 + lg * 4;
#pragma unroll
  for (int dt = 0; dt < 16; ++dt) {
    u16x4 o4;
#pragma unroll
    for (int r = 0; r < 4; ++r) o4[r] = f32_bf16(oacc[dt][r] * inv);
    *(u16x4*)(op + dt * 16) = o4;
  }
}

// ---------------- launch: 5 kernels ----------------
extern "C" void kernel_launch(void* const* d_in, const int* in_sizes, int n_in,
                              void* d_out, int out_size, void* d_ws, size_t ws_size,
                              hipStream_t stream) {
  const float* hidden = (const float*)d_in[0];
  // d_in[1]: attention_mask (pure causal; handled analytically)
  const int* pos_ids = (const int*)d_in[2];
  const float* Wq = (const float*)d_in[3];
  const float* Wk = (const float*)d_in[4];
  const float* Wv = (const float*)d_in[5];
  const float* Wo = (const float*)d_in[6];
  float* out = (float*)d_out;
  char* ws = (char*)d_ws;

  unsigned short* qkv_bf = (unsigned short*)(ws);              // 20 MB: [4096][2560]
  unsigned short* hid_bf = (unsigned short*)(ws + 20971520);   // 16 MB (reused as attn out)
  unsigned short* w_bf   = (unsigned short*)(ws + 37748736);   // 10 MB (Wq|Wk|Wv, later Wo)
  unsigned short* vtbuf  = (unsigned short*)(ws + 48234496);   // 2 MB [b][256][2048]
  float*          ctab   = (float*)(ws + 50331648);            // 2 MB
  float*          stab   = (float*)(ws + 52428800);            // 2 MB
  unsigned short* attno  = hid_bf;                             // alias: hidden dead after qkv GEMM

  // 1) all casts + rope table
  prep<<<15360, 256, 0, stream>>>(hidden, Wq, Wk, Wv, pos_ids, hid_bf, w_bf, ctab, stab);

  // 2) fused QKV projection (grid 640 blocks, %8==0)
  gemm_nt<0><<<dim3(20, 32), 256, 0, stream>>>(hid_bf, w_bf, qkv_bf, 4096, 2560, 2048);

  // 3) rope apply (+SCALE into Q) + V transpose + Wo cast (w_bf now free)
  mid<<<6656, 256, 0, stream>>>(qkv_bf, ctab, stab, vtbuf, Wo, w_bf);

  // 4) attention
  attn4<<<dim3(32, 8, 2), 256, 0, stream>>>(qkv_bf, vtbuf, attno);

  // 5) output projection (f32 out; grid 512 blocks, %8==0)
  gemm_nt<1><<<dim3(16, 32), 256, 0, stream>>>(attno, w_bf, out, 4096, 2048, 2048);
}